// Round 13
// baseline (128.332 us; speedup 1.0000x reference)
//
#include <hip/hip_runtime.h>
#include <hip/hip_cooperative_groups.h>
#include <stdint.h>

namespace cg = cooperative_groups;

// Single cooperative kernel, two phases separated by grid.sync():
//   phase 1 (prep): W fp32 -> Wq bf16 in GEMM-staging order [et:4][j:16][h:2][chunk:4][row:256][8]
//                   img (8,256,128,128) fp32 -> imgT[b][y][x][c] bf16 (LDS transpose)
//   phase 2 (gemm): R7-verified 256^2 8-wave 8-phase MFMA GEMM, counted vmcnt(4),
//                   A gathered in-staging from imgT per keypoint.
//   k' = (ky*2+kx)*256 + c; pixel (py,px) <-> (o,p): o=(py>>1)+2*(px>>1), p=(py&1)*2+(px&1)

typedef __attribute__((ext_vector_type(8))) short bf16x8;
typedef __attribute__((ext_vector_type(4))) float f32x4;

#define GAS(p) ((const __attribute__((address_space(1))) void*)(p))
#define LAS(p) ((__attribute__((address_space(3))) void*)(p))

__device__ __forceinline__ unsigned short f2bf(float f) {
    union { float f; uint32_t u; } x; x.f = f;
    uint32_t u = x.u;
    uint32_t r = (u + 0x7FFFu + ((u >> 16) & 1u)) >> 16;   // round-nearest-even
    return (unsigned short)r;
}

__global__ __launch_bounds__(512, 1)
void fused_kernel(const float* __restrict__ img, const float* __restrict__ Wf,
                  const float* __restrict__ bias,
                  const int* __restrict__ bidx, const int* __restrict__ pxid,
                  const int* __restrict__ pyid,
                  unsigned short* __restrict__ Wq, unsigned short* __restrict__ zp,
                  unsigned short* __restrict__ imgT, float* __restrict__ out)
{
    __shared__ unsigned short smem[65536];   // 128 KB, reused across phases
    const int blk = blockIdx.x;              // 256
    const int tid = threadIdx.x;             // 512

    // ================= PHASE 1: prep =================
    {
        if (blk == 0 && tid < 32) {
            uint4 z = {0, 0, 0, 0};
            ((uint4*)zp)[tid] = z;           // 512 B zeros for OOB staging
        }
        // ---- Wq: one 16B group per thread (131072 total) ----
        const int t  = blk * 512 + tid;
        const int et = t >> 15;
        const int r1 = t & 32767;
        const int j  = r1 >> 11;
        const int r2 = r1 & 2047;
        const int h  = r2 >> 10;
        const int r3 = r2 & 1023;
        const int chunk = r3 >> 8;
        const int row   = r3 & 255;
        const int e  = et * 256 + row;
        const int kb = j * 64 + h * 32 + chunk * 8;
        unsigned short v[8];
        #pragma unroll
        for (int kk = 0; kk < 8; ++kk) {
            const int k = kb + kk;           // k' in [0,1024)
            const int c = k & 255;
            const int p = k >> 8;
            v[kk] = f2bf(Wf[(size_t)e * 1024 + c * 4 + p]);
        }
        *(uint4*)&Wq[(size_t)t * 8] = *(const uint4*)v;

        // ---- imgt: 16 units per block, two independent 256-thread halves ----
        const int half = tid >> 8;           // 0..1
        const int lt   = tid & 255;
        unsigned int* sU = (unsigned int*)&smem[half * 8192];
        const int xq = lt & 31;              // x = xq*4 + jj
        const int ch = lt >> 5;              // 0..7 (c-pair subgroup)
        #pragma unroll 1
        for (int i = 0; i < 8; ++i) {
            const int u  = blk * 16 + half * 8 + i;   // 0..4095
            const int cc = u & 3;
            const int y  = (u >> 2) & 127;
            const int b  = u >> 9;
            const size_t pl = ((size_t)b * 256 + cc * 64) * 16384 + (size_t)y * 128;
            #pragma unroll
            for (int it = 0; it < 4; ++it) {
                const int cp = it * 8 + ch;  // c-pair 0..31
                const float4 v0 = *(const float4*)&img[pl + (size_t)(2 * cp)     * 16384 + xq * 4];
                const float4 v1 = *(const float4*)&img[pl + (size_t)(2 * cp + 1) * 16384 + xq * 4];
                const float a0[4] = {v0.x, v0.y, v0.z, v0.w};
                const float a1[4] = {v1.x, v1.y, v1.z, v1.w};
                #pragma unroll
                for (int jj = 0; jj < 4; ++jj) {
                    const int x = xq * 4 + jj;
                    const unsigned int pk = (unsigned)f2bf(a0[jj]) | ((unsigned)f2bf(a1[jj]) << 16);
                    sU[x * 32 + (cp ^ (x & 31))] = pk;
                }
            }
            __syncthreads();
            unsigned short* ob = imgT + (((size_t)b * 128 + y) * 128) * 256 + cc * 64;
            #pragma unroll
            for (int jj = 0; jj < 16; ++jj) {
                const int oo = lt + 256 * jj;         // 0..4095
                const int xx = oo >> 5;
                const int c2 = oo & 31;
                const unsigned int pk = sU[xx * 32 + (c2 ^ (xx & 31))];
                *(unsigned int*)&ob[(size_t)xx * 256 + c2 * 2] = pk;
            }
            __syncthreads();
        }
    }

    cg::this_grid().sync();                  // prep results visible grid-wide

    // ================= PHASE 2: gemm (R7 structure verbatim) =================
    unsigned short* sW = smem;               // 2 bufs x 16384 shorts (64 KB)
    unsigned short* sA = smem + 32768;       // 2 bufs x 16384 shorts (64 KB)

    const int orig = blk;                    // 256
    const int xcd  = orig & 7;
    const int s    = orig >> 3;              // 0..31
    const int gnt  = xcd * 8 + (s >> 2);     // 64 gn-tiles of 256; e-siblings share XCD
    const int et2  = s & 3;                  // 4 e-tiles of 256
    const int e0   = et2 * 256;
    const int g    = gnt >> 1;
    const int n0   = (gnt & 1) * 256;
    const int b = g >> 2, o = g & 3;

    const int lane = tid & 63;
    const int wid  = tid >> 6;
    const int wm   = wid >> 2;               // 0..1 -> e rows wm*128
    const int wn   = wid & 3;                // 0..3 -> n cols wn*64

    int ayv[2], axv[2];
    size_t apl[2];
    #pragma unroll
    for (int u = 0; u < 2; ++u) {
        const int row = u * 128 + (tid >> 2);
        const int gi = b * 512 + n0 + row;
        apl[u] = (size_t)bidx[gi] * (128 * 128 * 256);
        ayv[u] = 2 * pyid[gi] - 1 + (o & 1) * 2;    // + (p>>1) at stage time
        axv[u] = 2 * pxid[gi] - 1 + (o >> 1) * 2;   // + (p&1)
    }
    const int aswz = (((tid & 3) ^ ((tid >> 3) & 3))) * 8;  // pre-swizzled chunk (shorts)
    const unsigned short* wq_base = Wq + (size_t)et2 * 262144 + tid * 8;

    f32x4 acc[8][4];
    #pragma unroll
    for (int m = 0; m < 8; ++m)
        #pragma unroll
        for (int nf = 0; nf < 4; ++nf) acc[m][nf] = (f32x4){0.f, 0.f, 0.f, 0.f};

    auto stageHalf = [&](int j, int h, int buf) {
        #pragma unroll
        for (int u = 0; u < 2; ++u) {
            const unsigned short* src = wq_base + (size_t)(j * 2 + h) * 8192 + u * 4096;
            __builtin_amdgcn_global_load_lds(GAS(src),
                LAS(&sW[buf * 16384 + h * 8192 + u * 4096 + tid * 8]), 16, 0, 0);
        }
        const int p = j >> 2;
        const int csh = (j & 3) * 64 + h * 32 + aswz;
        #pragma unroll
        for (int u = 0; u < 2; ++u) {
            const int yy = ayv[u] + (p >> 1);
            const int xx = axv[u] + (p & 1);
            const unsigned short* src =
                ((unsigned)yy < 128u && (unsigned)xx < 128u)
                    ? imgT + apl[u] + ((size_t)(yy * 128 + xx)) * 256 + csh
                    : zp + aswz;
            __builtin_amdgcn_global_load_lds(GAS(src),
                LAS(&sA[buf * 16384 + h * 8192 + u * 4096 + tid * 8]), 16, 0, 0);
        }
    };

    stageHalf(0, 0, 0);
    stageHalf(0, 1, 0);

    for (int j = 0; j < 16; ++j) {
        const int buf = j & 1;
        #pragma unroll
        for (int h = 0; h < 2; ++h) {
            if (j == 15 && h == 1) { asm volatile("s_waitcnt vmcnt(0)" ::: "memory"); }
            else                   { asm volatile("s_waitcnt vmcnt(4)" ::: "memory"); }
            __builtin_amdgcn_s_barrier();
            if (j < 15) stageHalf(j + 1, h, buf ^ 1);

            bf16x8 af[8];
            {
                const int chunk = lane >> 4;
                const int rb = wm * 128 + (lane & 15);
                #pragma unroll
                for (int m = 0; m < 8; ++m)
                    af[m] = *(const bf16x8*)&sW[buf * 16384 + h * 8192 + chunk * 2048 + (rb + m * 16) * 8];
            }
            #pragma unroll
            for (int nh = 0; nh < 2; ++nh) {
                bf16x8 bfr[2];
                #pragma unroll
                for (int nn = 0; nn < 2; ++nn) {
                    const int row = wn * 64 + (nh * 2 + nn) * 16 + (lane & 15);
                    const int perm = (lane >> 4) ^ ((row >> 1) & 3);
                    bfr[nn] = *(const bf16x8*)&sA[buf * 16384 + h * 8192 + row * 32 + perm * 8];
                }
                __builtin_amdgcn_s_setprio(1);
                #pragma unroll
                for (int m = 0; m < 8; ++m)
                    #pragma unroll
                    for (int nn = 0; nn < 2; ++nn)
                        acc[m][nh * 2 + nn] = __builtin_amdgcn_mfma_f32_16x16x32_bf16(
                            af[m], bfr[nn], acc[m][nh * 2 + nn], 0, 0, 0);
                __builtin_amdgcn_s_setprio(0);
            }
        }
    }

    // ---- epilogue: D row(e) = (lane>>4)*4+reg, col(n) = lane&15 ----
    #pragma unroll
    for (int m = 0; m < 8; ++m) {
        const int eb = e0 + wm * 128 + m * 16 + (lane >> 4) * 4;
        float bv[4];
        #pragma unroll
        for (int reg = 0; reg < 4; ++reg) bv[reg] = bias[eb + reg];
        #pragma unroll
        for (int nf = 0; nf < 4; ++nf) {
            const int nn = n0 + wn * 64 + nf * 16 + (lane & 15);
            #pragma unroll
            for (int reg = 0; reg < 4; ++reg)
                out[((size_t)g * 1024 + eb + reg) * 512 + nn] = acc[m][nf][reg] + bv[reg];
        }
    }
}

extern "C" void kernel_launch(void* const* d_in, const int* in_sizes, int n_in,
                              void* d_out, int out_size, void* d_ws, size_t ws_size,
                              hipStream_t stream) {
    const float* img  = (const float*)d_in[0];
    const float* Wf   = (const float*)d_in[1];
    const float* bias = (const float*)d_in[2];
    const int*   bidx = (const int*)d_in[3];
    const int*   pxid = (const int*)d_in[4];
    const int*   pyid = (const int*)d_in[5];
    float* out = (float*)d_out;

    unsigned short* Wq   = (unsigned short*)((char*)d_ws + (32u << 20));  // 2 MiB
    unsigned short* zp   = (unsigned short*)((char*)d_ws + (36u << 20));  // 512 B zeros
    unsigned short* imgT = (unsigned short*)((char*)d_ws + (64u << 20));  // 64 MiB

    void* args[] = {(void*)&img, (void*)&Wf, (void*)&bias, (void*)&bidx,
                    (void*)&pxid, (void*)&pyid, (void*)&Wq, (void*)&zp,
                    (void*)&imgT, (void*)&out};
    hipLaunchCooperativeKernel((const void*)fused_kernel, dim3(256), dim3(512),
                               args, 0, stream);
}

// Round 16
// 80.902 us; speedup vs baseline: 1.5863x; 1.5863x over previous
//
#include <hip/hip_runtime.h>
#include <stdint.h>

// Pipeline (k' = (ky*2+kx)*256 + c ordering for the GEMM K axis):
//   0. prep : blocks 0..511    -> W fp32 -> Wq in GEMM-staging order (chunk-major) bf16
//             blocks 512..4607 -> img (8,256,128,128) fp32 -> imgT[b][y][x][c] bf16
//   1. gemm : 256x256-tile 8-wave MFMA GEMM, 8-phase schedule, counted vmcnt(4)
//             (never 0 in loop), A gathered in-staging from imgT per keypoint.
//             R15 = R7 verbatim + A-base computation hoisted to once-per-tile,
//             BEFORE the vmcnt wait (overlaps prior compute; T14-lite).
//      pixel (py,px) <-> (o,p): o=(py>>1)+2*(px>>1), p=(py&1)*2+(px&1)

typedef __attribute__((ext_vector_type(8))) short bf16x8;
typedef __attribute__((ext_vector_type(4))) float f32x4;

#define GAS(p) ((const __attribute__((address_space(1))) void*)(p))
#define LAS(p) ((__attribute__((address_space(3))) void*)(p))

__device__ __forceinline__ unsigned short f2bf(float f) {
    union { float f; uint32_t u; } x; x.f = f;
    uint32_t u = x.u;
    uint32_t r = (u + 0x7FFFu + ((u >> 16) & 1u)) >> 16;   // round-nearest-even
    return (unsigned short)r;
}

// ---------------- Stage 0: fused W-reorder (staging order) + img transpose ----------------
__global__ __launch_bounds__(256)
void prep_kernel(const float* __restrict__ img, const float* __restrict__ Wf,
                 unsigned short* __restrict__ Wq, unsigned short* __restrict__ zp,
                 unsigned short* __restrict__ imgT) {
    __shared__ unsigned short sT[8192];
    const int blk = blockIdx.x;
    const int tid = threadIdx.x;

    if (blk < 512) {                        // ---- Wq: one thread = 8 k's of one (et,j,h,chunk,row)
        if (blk == 0 && tid < 32) {
            uint4 z = {0, 0, 0, 0};
            ((uint4*)zp)[tid] = z;          // 512 B zeros for OOB staging
        }
        const int t  = blk * 256 + tid;     // 0..131071
        const int et = t >> 15;
        const int r1 = t & 32767;
        const int j  = r1 >> 11;
        const int r2 = r1 & 2047;
        const int h  = r2 >> 10;
        const int r3 = r2 & 1023;
        const int chunk = r3 >> 8;
        const int row   = r3 & 255;
        const int e  = et * 256 + row;
        const int kb = j * 64 + h * 32 + chunk * 8;
        unsigned short v[8];
        #pragma unroll
        for (int kk = 0; kk < 8; ++kk) {
            const int k = kb + kk;          // k' in [0,1024)
            const int c = k & 255;
            const int p = k >> 8;
            v[kk] = f2bf(Wf[(size_t)e * 1024 + c * 4 + p]);
        }
        *(uint4*)&Wq[(size_t)t * 8] = *(const uint4*)v;
        return;
    }

    // ---- imgt: block = (b, y, c-chunk of 64); float4-vectorized reads ----
    const int ib = blk - 512;               // 0..4095
    const int cc = ib & 3;
    const int y  = (ib >> 2) & 127;
    const int b  = ib >> 9;
    const int xq = tid & 31;                // x-quad: x = xq*4 + jj
    const int ch = tid >> 5;                // 0..7 (c-pair subgroup)
    unsigned int* sU = (unsigned int*)sT;
    const size_t pl = ((size_t)b * 256 + cc * 64) * 16384 + (size_t)y * 128;
    #pragma unroll
    for (int it = 0; it < 4; ++it) {
        const int cp = it * 8 + ch;         // c-pair 0..31
        const float4 v0 = *(const float4*)&img[pl + (size_t)(2 * cp)     * 16384 + xq * 4];
        const float4 v1 = *(const float4*)&img[pl + (size_t)(2 * cp + 1) * 16384 + xq * 4];
        const float a0[4] = {v0.x, v0.y, v0.z, v0.w};
        const float a1[4] = {v1.x, v1.y, v1.z, v1.w};
        #pragma unroll
        for (int jj = 0; jj < 4; ++jj) {
            const int x = xq * 4 + jj;
            const unsigned int pk = (unsigned)f2bf(a0[jj]) | ((unsigned)f2bf(a1[jj]) << 16);
            sU[x * 32 + (cp ^ (x & 31))] = pk;
        }
    }
    __syncthreads();
    unsigned short* ob = imgT + (((size_t)b * 128 + y) * 128) * 256 + cc * 64;
    #pragma unroll
    for (int jj = 0; jj < 16; ++jj) {
        const int oo = tid + 256 * jj;      // 0..4095
        const int xx = oo >> 5;
        const int c2 = oo & 31;
        const unsigned int pk = sU[xx * 32 + (c2 ^ (xx & 31))];
        *(unsigned int*)&ob[(size_t)xx * 256 + c2 * 2] = pk;
    }
}

// ---------------- Stage 1: fused-gather 256^2 8-phase MFMA GEMM ----------------
// 256 blocks (1/CU), 512 threads (8 waves 2m x 4n). 16 K-tiles of BK=64,
// each tile = 2 K-halves; per half: vmcnt(4)+barrier, issue next-tile half's
// 4 staging insts (A = hoisted base + h*32, compiler folds to imm), ds_read
// af[8] (W, conflict-free), then 2 phases of {ds_read bf[2], setprio, 16 MFMA}.
__global__ __launch_bounds__(512, 1)
void gemm_kernel(const unsigned short* __restrict__ Wq,
                 const unsigned short* __restrict__ imgT,
                 const unsigned short* __restrict__ zp,
                 const int* __restrict__ bidx,
                 const int* __restrict__ pxid,
                 const int* __restrict__ pyid,
                 const float* __restrict__ bias,
                 float* __restrict__ out)
{
    const int orig = blockIdx.x;            // 256
    const int xcd  = orig & 7;
    const int s    = orig >> 3;             // 0..31
    const int gnt  = xcd * 8 + (s >> 2);    // 64 gn-tiles of 256; e-siblings share XCD
    const int et   = s & 3;                 // 4 e-tiles of 256
    const int e0   = et * 256;
    const int g    = gnt >> 1;
    const int n0   = (gnt & 1) * 256;
    const int b = g >> 2, o = g & 3;

    const int tid  = threadIdx.x;
    const int lane = tid & 63;
    const int wid  = tid >> 6;
    const int wm   = wid >> 2;              // 0..1 -> e rows wm*128
    const int wn   = wid & 3;               // 0..3 -> n cols wn*64

    __shared__ unsigned short sW[2 * 16384]; // [buf][h:2][chunk:4][row:256][8]
    __shared__ unsigned short sA[2 * 16384]; // [buf][h:2][row:256][slot:4][8]

    // ---- A stage descriptors: thread -> rows u*128 + tid/4, 16B chunk (tid&3) ----
    int ayv[2], axv[2];
    size_t apl[2];
    #pragma unroll
    for (int u = 0; u < 2; ++u) {
        const int row = u * 128 + (tid >> 2);
        const int gi = b * 512 + n0 + row;
        apl[u] = (size_t)bidx[gi] * (128 * 128 * 256);
        ayv[u] = 2 * pyid[gi] - 1 + (o & 1) * 2;   // + (p>>1) at stage time
        axv[u] = 2 * pxid[gi] - 1 + (o >> 1) * 2;  // + (p&1)
    }
    const int aswz = (((tid & 3) ^ ((tid >> 3) & 3))) * 8;  // pre-swizzled chunk (shorts)
    const unsigned short* wq_base = Wq + (size_t)et * 262144 + tid * 8;

    f32x4 acc[8][4];
    #pragma unroll
    for (int m = 0; m < 8; ++m)
        #pragma unroll
        for (int nf = 0; nf < 4; ++nf) acc[m][nf] = (f32x4){0.f, 0.f, 0.f, 0.f};

    // hoisted A base pointers for the tile being STAGED (bounds + zp folded in;
    // includes the (jn&3)*64 window offset; stageHalf adds only h*32)
    const unsigned short* ab[2];
    auto mkbase = [&](int jn) {
        const int pn = jn >> 2;
        #pragma unroll
        for (int u = 0; u < 2; ++u) {
            const int yy = ayv[u] + (pn >> 1);
            const int xx = axv[u] + (pn & 1);
            ab[u] = ((unsigned)yy < 128u && (unsigned)xx < 128u)
                        ? imgT + apl[u] + ((size_t)(yy * 128 + xx)) * 256 + (jn & 3) * 64 + aswz
                        : zp + aswz;
        }
    };

    auto stageHalf = [&](int jn, int h, int buf) {
        #pragma unroll
        for (int u = 0; u < 2; ++u) {
            const unsigned short* wsrc = wq_base + (size_t)(jn * 2 + h) * 8192 + u * 4096;
            __builtin_amdgcn_global_load_lds(GAS(wsrc),
                LAS(&sW[buf * 16384 + h * 8192 + u * 4096 + tid * 8]), 16, 0, 0);
        }
        #pragma unroll
        for (int u = 0; u < 2; ++u) {
            __builtin_amdgcn_global_load_lds(GAS(ab[u] + h * 32),
                LAS(&sA[buf * 16384 + h * 8192 + u * 4096 + tid * 8]), 16, 0, 0);
        }
    };

    // prologue: tile 0 fully staged (8 insts in flight)
    mkbase(0);
    stageHalf(0, 0, 0);
    stageHalf(0, 1, 0);

    for (int j = 0; j < 16; ++j) {
        const int buf = j & 1;
        if (j < 15) mkbase(j + 1);          // address calc overlaps prior compute
        #pragma unroll
        for (int h = 0; h < 2; ++h) {
            // complete the oldest half (tile j, half h); keep the rest in flight
            if (j == 15 && h == 1) { asm volatile("s_waitcnt vmcnt(0)" ::: "memory"); }
            else                   { asm volatile("s_waitcnt vmcnt(4)" ::: "memory"); }
            __builtin_amdgcn_s_barrier();
            if (j < 15) stageHalf(j + 1, h, buf ^ 1);   // 4 insts into the other dbuf

            // W fragments for this K-half (reused across both n-half phases)
            bf16x8 af[8];
            {
                const int chunk = lane >> 4;
                const int rb = wm * 128 + (lane & 15);
                #pragma unroll
                for (int m = 0; m < 8; ++m)
                    af[m] = *(const bf16x8*)&sW[buf * 16384 + h * 8192 + chunk * 2048 + (rb + m * 16) * 8];
            }
            #pragma unroll
            for (int nh = 0; nh < 2; ++nh) {
                bf16x8 bfr[2];
                #pragma unroll
                for (int nn = 0; nn < 2; ++nn) {
                    const int row = wn * 64 + (nh * 2 + nn) * 16 + (lane & 15);
                    const int perm = (lane >> 4) ^ ((row >> 1) & 3);
                    bfr[nn] = *(const bf16x8*)&sA[buf * 16384 + h * 8192 + row * 32 + perm * 8];
                }
                __builtin_amdgcn_s_setprio(1);
                #pragma unroll
                for (int m = 0; m < 8; ++m)
                    #pragma unroll
                    for (int nn = 0; nn < 2; ++nn)
                        acc[m][nh * 2 + nn] = __builtin_amdgcn_mfma_f32_16x16x32_bf16(
                            af[m], bfr[nn], acc[m][nh * 2 + nn], 0, 0, 0);
                __builtin_amdgcn_s_setprio(0);
            }
        }
    }

    // ---- epilogue: D row(e) = (lane>>4)*4+reg, col(n) = lane&15 ----
    #pragma unroll
    for (int m = 0; m < 8; ++m) {
        const int eb = e0 + wm * 128 + m * 16 + (lane >> 4) * 4;
        float bv[4];
        #pragma unroll
        for (int reg = 0; reg < 4; ++reg) bv[reg] = bias[eb + reg];
        #pragma unroll
        for (int nf = 0; nf < 4; ++nf) {
            const int nn = n0 + wn * 64 + nf * 16 + (lane & 15);
            #pragma unroll
            for (int reg = 0; reg < 4; ++reg)
                out[((size_t)g * 1024 + eb + reg) * 512 + nn] = acc[m][nf][reg] + bv[reg];
        }
    }
}

extern "C" void kernel_launch(void* const* d_in, const int* in_sizes, int n_in,
                              void* d_out, int out_size, void* d_ws, size_t ws_size,
                              hipStream_t stream) {
    const float* img  = (const float*)d_in[0];
    const float* Wf   = (const float*)d_in[1];
    const float* bias = (const float*)d_in[2];
    const int*   bidx = (const int*)d_in[3];
    const int*   pxid = (const int*)d_in[4];
    const int*   pyid = (const int*)d_in[5];
    float* out = (float*)d_out;

    unsigned short* Wq   = (unsigned short*)((char*)d_ws + (32u << 20));  // 2 MiB
    unsigned short* zp   = (unsigned short*)((char*)d_ws + (36u << 20));  // 512 B zeros
    unsigned short* imgT = (unsigned short*)((char*)d_ws + (64u << 20));  // 64 MiB

    hipLaunchKernelGGL(prep_kernel, dim3(4608), dim3(256), 0, stream,
                       img, Wf, Wq, zp, imgT);
    hipLaunchKernelGGL(gemm_kernel, dim3(256), dim3(512), 0, stream,
                       Wq, imgT, zp, bidx, pxid, pyid, bias, out);
}